// Round 7
// baseline (21.547 us; speedup 1.0000x reference)
//
#include <hip/hip_runtime.h>
#include <math.h>

// SMorphLayer: B=8, C=1, H=W=128, F=16, KH=KW=5, stride 1 -> OH=OW=124
// y[b,f,oy,ox] = sm(p + k1[f]) + sm(-p + k2[f]) + bias[f],
// sm(t) = sum(t e^t)/sum(e^t) (alpha=1, max-shift cancels exactly).
// Factorization: e^{p_j+k1_fj} = E_j*e1_fj, E_j=e^{p_j}, I_j=1/E_j:
//   n1 = sum_j fma(p, e1, k1e1)*E   d1 = sum_j E*e1
//   n2 = sum_j fma(-p, e2, k2e2)*I  d2 = sum_j I*e2
//
// Round-6: kill the DS constant traffic structurally. Constants live in
// GLOBAL (precomputed into d_ws); main kernel reads them at block-uniform
// indices -> scalar s_load (SGPRs), not LDS broadcasts, not VGPRs. LDS
// holds only the input tile. I = v_rcp(E) replaces exp(-p). Live set
// ~90 VGPR -> 4 waves/SIMD, all 1024 blocks resident in one round.

#define Bn 8
#define Fn 16
#define Hn 128
#define Wn 128
#define OHn 124
#define OWn 124
#define FSPLIT 8
#define FPB (Fn / FSPLIT)   // 2 filters per block
#define ROWS 8              // output rows per block
#define TW 132              // tile row stride in floats (16B aligned)
#define TR 12               // tile rows (8 + 4)

__global__ __launch_bounds__(256) void smorph_precompute(
    const float* __restrict__ k1, const float* __restrict__ k2,
    float4* __restrict__ cc /* [16*25] = {e1, k1*e1, e2, k2*e2} */) {
  int i = blockIdx.x * 256 + threadIdx.x;
  if (i < Fn * 25) {
    const float a = k1[i], c = k2[i];
    const float e1 = __expf(a), e2 = __expf(c);
    cc[i] = make_float4(e1, a * e1, e2, c * e2);
  }
}

__global__ __launch_bounds__(256) void smorph_main(
    const float* __restrict__ x, const float4* __restrict__ cc,
    const float* __restrict__ bias, float* __restrict__ out) {
  __shared__ float tile[TR][TW];  // 12 x 132 x 4B = 6336 B (only LDS use)

  const int z = blockIdx.z;
  const int b = z >> 3, fh = z & 7;
  const int y0 = blockIdx.y * ROWS;
  const int tid = threadIdx.x;
  const float* xb = x + b * (Hn * Wn);

  // Stage 12x132 input tile as float4 (zero-pad outside image).
  for (int i = tid; i < TR * (TW / 4); i += 256) {
    const int r = i / (TW / 4), c4 = i % (TW / 4);
    const int gy = y0 + r, gx = c4 * 4;
    float4 v = make_float4(0.f, 0.f, 0.f, 0.f);
    if (gy < Hn && gx < Wn) v = *(const float4*)&xb[gy * Wn + gx];
    *(float4*)&tile[r][gx] = v;
  }
  __syncthreads();

  const int xi = tid & 31;   // leftmost output col = 4*xi
  const int ly = tid >> 5;   // output row within block
  const int oy = y0 + ly;
  if (oy >= OHn || xi >= 31) return;  // no barriers below

  float n1[FPB][4], d1[FPB][4], n2[FPB][4], d2[FPB][4];
#pragma unroll
  for (int fi = 0; fi < FPB; ++fi)
#pragma unroll
    for (int q = 0; q < 4; ++q) {
      n1[fi][q] = 0.f; d1[fi][q] = 0.f; n2[fi][q] = 0.f; d2[fi][q] = 0.f;
    }

#pragma unroll 1  // real loop: bounds live range of row state + constants
  for (int kh = 0; kh < 5; ++kh) {
    // 8 row floats cover all kw+q windows: 2 aligned ds_read_b128.
    const float* rowp = &tile[ly + kh][xi * 4];
    const float4 ra = *(const float4*)rowp;
    const float4 rb = *(const float4*)(rowp + 4);
    const float r[8] = {ra.x, ra.y, ra.z, ra.w, rb.x, rb.y, rb.z, rb.w};
    float Er[8], Ir[8];
#pragma unroll
    for (int c = 0; c < 8; ++c) {
      Er[c] = __expf(r[c]);
      Ir[c] = __builtin_amdgcn_rcpf(Er[c]);  // e^-p = 1/e^p (1 ulp, fine)
    }
#pragma unroll
    for (int kw = 0; kw < 5; ++kw) {
#pragma unroll
      for (int fi = 0; fi < FPB; ++fi) {
        // Block-uniform global index -> scalar load into SGPRs.
        const float4 v = cc[(fh * FPB + fi) * 25 + kh * 5 + kw];
#pragma unroll
        for (int q = 0; q < 4; ++q) {
          const float p = r[kw + q], E = Er[kw + q], I = Ir[kw + q];
          const float t1 = fmaf(p, v.x, v.y);
          n1[fi][q] = fmaf(t1, E, n1[fi][q]);
          d1[fi][q] = fmaf(E, v.x, d1[fi][q]);
          const float t2 = fmaf(-p, v.z, v.w);
          n2[fi][q] = fmaf(t2, I, n2[fi][q]);
          d2[fi][q] = fmaf(I, v.z, d2[fi][q]);
        }
      }
    }
  }

#pragma unroll
  for (int fi = 0; fi < FPB; ++fi) {
    const float bv = bias[fh * FPB + fi];  // uniform -> s_load
    float4 o;
    o.x = __fdividef(n1[fi][0], d1[fi][0]) + __fdividef(n2[fi][0], d2[fi][0]) + bv;
    o.y = __fdividef(n1[fi][1], d1[fi][1]) + __fdividef(n2[fi][1], d2[fi][1]) + bv;
    o.z = __fdividef(n1[fi][2], d1[fi][2]) + __fdividef(n2[fi][2], d2[fi][2]) + bv;
    o.w = __fdividef(n1[fi][3], d1[fi][3]) + __fdividef(n2[fi][3], d2[fi][3]) + bv;
    *(float4*)&out[((b * Fn + fh * FPB + fi) * OHn + oy) * OWn + xi * 4] = o;
  }
}

extern "C" void kernel_launch(void* const* d_in, const int* in_sizes, int n_in,
                              void* d_out, int out_size, void* d_ws, size_t ws_size,
                              hipStream_t stream) {
  const float* x    = (const float*)d_in[0];
  const float* k1   = (const float*)d_in[1];
  const float* k2   = (const float*)d_in[2];
  const float* bias = (const float*)d_in[3];
  float* out = (float*)d_out;
  float4* cc = (float4*)d_ws;  // 400 * 16 B = 6400 B

  smorph_precompute<<<2, 256, 0, stream>>>(k1, k2, cc);
  dim3 grid(1, (OHn + ROWS - 1) / ROWS, Bn * FSPLIT);  // (1, 16, 64)
  smorph_main<<<grid, 256, 0, stream>>>(x, cc, bias, out);
}